// Round 5
// baseline (90.059 us; speedup 1.0000x reference)
//
#include <hip/hip_runtime.h>
#include <math.h>

#define D 20
#define NROWS 1000000
#define NTILES (NROWS / 16)          // 62500 16-row tiles
#define TPB 256
#define NBLK 2048                    // 8 blocks/CU -> 8 waves/SIMD, all-resident
#define WT (NBLK * (TPB / 64))       // 8192 waves

typedef float  f32x4  __attribute__((ext_vector_type(4)));
typedef __bf16 bf16x8 __attribute__((ext_vector_type(8)));

// ws layout: [0, NBLK*16) partial (S,Sabs) doubles; [NBLK*16, +4) atomic counter
// counter zeroed by hipMemsetAsync graph node every launch -> poison/replay safe.
#define CNT_OFF (NBLK * 16)

// ---------------------------------------------------------------------------
// Per-lane MFMA constant-fragment builders (16x16x32 bf16).
// B1 (GEMM1 A-operand): row m=mbase+ii, k=G*8+e indexes j of A[j][m]; k==20 -> c[m].
// B2 (GEMM2 B-operand): col n=nbase+ii, SIGMA-permuted k-rows
//   sigma(G,e) = e<4 ? 4G+e : 16+4G+(e-4); sigma==20 -> b[n]. Permutation chosen
//   so GEMM1 accumulator regs feed GEMM2's A-fragment with NO cross-lane ops.
// ---------------------------------------------------------------------------
__device__ inline bf16x8 mk_frag_b1(const float* A_s, const float* c_s,
                                    int G, int ii, int mbase) {
  bf16x8 f;
#pragma unroll
  for (int e = 0; e < 8; ++e) {
    int k = G * 8 + e;
    int m = mbase + ii;
    float v = 0.f;
    if (m < D) v = (k < D) ? A_s[k * D + m] : (k == D ? c_s[m] : 0.f);
    f[e] = (__bf16)v;
  }
  return f;
}
__device__ inline bf16x8 mk_frag_b2(const float* __restrict__ W,
                                    const float* __restrict__ b,
                                    int G, int ii, int nbase) {
  bf16x8 f;
#pragma unroll
  for (int e = 0; e < 8; ++e) {
    int sg = (e < 4) ? (4 * G + e) : (16 + 4 * G + (e - 4));
    int n = nbase + ii;
    float v = 0.f;
    if (n < D) v = (sg < D) ? W[n * D + sg] : (sg == D ? b[n] : 0.f);
    f[e] = (__bf16)v;
  }
  return f;
}

// ---------------------------------------------------------------------------
// ONE fused kernel. Main loop is BRANCHLESS: every lane issues both 16B loads
// every iteration (clamped, always in-bounds); lane-masking happens in the
// fragment build via cndmask. Only control flow = wave-uniform loop backedge.
// 8 waves/SIMD provide TLP latency cover; 1-deep prefetch.
// ---------------------------------------------------------------------------
__global__ __launch_bounds__(TPB, 8) void fused_kernel(
    const float* __restrict__ X, const float* __restrict__ W,
    const float* __restrict__ b, const float* __restrict__ R,
    double* __restrict__ partial, unsigned int* __restrict__ counter,
    float* __restrict__ out) {
  __shared__ float A_s[D * D];
  __shared__ float c_s[D];
  __shared__ double red[8];
  __shared__ int amLast;
  const int tid = threadIdx.x;

  // ---- per-block fold of the first two layers (A = W^T R, c = bR + 1) ----
  for (int t = tid; t < D * D + D; t += TPB) {
    if (t < D * D) {
      int j = t / D, m = t % D;
      float s = 0.f;
#pragma unroll
      for (int i = 0; i < D; ++i) s = fmaf(W[i * D + j], R[i * D + m], s);
      A_s[t] = s;
    } else {
      int m = t - D * D;
      float s = 1.0f;
#pragma unroll
      for (int i = 0; i < D; ++i) s = fmaf(b[i], R[i * D + m], s);
      c_s[m] = s;
    }
  }
  __syncthreads();

  const int lane = tid & 63;
  const int G = lane >> 4, ii = lane & 15;
  const int wid = tid >> 6;
  const bf16x8 B1t1 = mk_frag_b1(A_s, c_s, G, ii, 0);
  const bf16x8 B1t2 = mk_frag_b1(A_s, c_s, G, ii, 16);
  const bf16x8 B2t1 = mk_frag_b2(W, b, G, ii, 0);
  const bf16x8 B2t2 = mk_frag_b2(W, b, G, ii, 16);

  // lane masks (hoisted out of the loop by the compiler; selects stay cheap)
  const bool mA = (G < 3);   // xf[0..3] valid
  const bool mB = (G < 2);   // xf[5..7] valid and xf[4]=cb.x
  // in-bounds per-lane load offsets (G>=2/G>=3 lanes load discarded data
  // from their OWN row -> never out of bounds, no extra cache lines)
  const int paOff = mA ? G * 8 : 0;
  const int pbOff = mB ? G * 8 + 4 : 4;
  const float* baseA = X + (size_t)ii * D + paOff;
  const float* baseB = X + (size_t)ii * D + pbOff;

  const int gw = blockIdx.x * (TPB / 64) + wid;
  double s64 = 0.0, sa64 = 0.0;

  // 1-deep prefetch, branchless
  float4 xa = *(const float4*)(baseA + (size_t)(gw < NTILES ? gw : 0) * (16 * D));
  float4 xb = *(const float4*)(baseB + (size_t)(gw < NTILES ? gw : 0) * (16 * D));

  for (int t = gw; t < NTILES; t += WT) {
    const float4 ca = xa, cb = xb;
    int tn = t + WT;
    int tc = (tn < NTILES) ? tn : (NTILES - 1);       // wave-uniform clamp
    xa = *(const float4*)(baseA + (size_t)tc * (16 * D));
    xb = *(const float4*)(baseB + (size_t)tc * (16 * D));

    // build X fragment: k = G*8+e ; k==20 (G==2,e==4) -> 1.0 ; k>20 -> 0
    bf16x8 xf;
    xf[0] = (__bf16)(mA ? ca.x : 0.f);
    xf[1] = (__bf16)(mA ? ca.y : 0.f);
    xf[2] = (__bf16)(mA ? ca.z : 0.f);
    xf[3] = (__bf16)(mA ? ca.w : 0.f);
    xf[4] = (__bf16)(mB ? cb.x : (G == 2 ? 1.0f : 0.f));
    xf[5] = (__bf16)(mB ? cb.y : 0.f);
    xf[6] = (__bf16)(mB ? cb.z : 0.f);
    xf[7] = (__bf16)(mB ? cb.w : 0.f);

    const f32x4 zz = {0.f, 0.f, 0.f, 0.f};
    f32x4 a1 = __builtin_amdgcn_mfma_f32_16x16x32_bf16(B1t1, xf, zz, 0, 0, 0);
    f32x4 a2 = __builtin_amdgcn_mfma_f32_16x16x32_bf16(B1t2, xf, zz, 0, 0, 0);
#pragma unroll
    for (int q = 0; q < 4; ++q) {
      a1[q] = fmaxf(a1[q], 0.f);
      a2[q] = fmaxf(a2[q], 0.f);
    }
    const float hj = (G == 1) ? 1.0f : a2[0];  // m=20 slot carries 1.0 (b-row)
    bf16x8 x2f;
    x2f[0] = (__bf16)a1[0]; x2f[1] = (__bf16)a1[1];
    x2f[2] = (__bf16)a1[2]; x2f[3] = (__bf16)a1[3];
    x2f[4] = (__bf16)hj;    x2f[5] = (__bf16)a2[1];
    x2f[6] = (__bf16)a2[2]; x2f[7] = (__bf16)a2[3];

    f32x4 z1 = __builtin_amdgcn_mfma_f32_16x16x32_bf16(x2f, B2t1, zz, 0, 0, 0);
    f32x4 z2 = __builtin_amdgcn_mfma_f32_16x16x32_bf16(x2f, B2t2, zz, 0, 0, 0);

    const float s8 = ((z1[0] + z1[1]) + (z1[2] + z1[3])) +
                     ((z2[0] + z2[1]) + (z2[2] + z2[3]));
    const float sa8 =
        ((fabsf(z1[0]) + fabsf(z1[1])) + (fabsf(z1[2]) + fabsf(z1[3]))) +
        ((fabsf(z2[0]) + fabsf(z2[1])) + (fabsf(z2[2]) + fabsf(z2[3])));
    s64 += (double)s8;
    sa64 += (double)sa8;
  }

  // ---- block reduce: wave64 shfl (f64) -> 4-wave LDS -> one pair/block ----
#pragma unroll
  for (int off = 32; off > 0; off >>= 1) {
    s64 += __shfl_down(s64, off, 64);
    sa64 += __shfl_down(sa64, off, 64);
  }
  if ((tid & 63) == 0) { red[wid * 2] = s64; red[wid * 2 + 1] = sa64; }
  __syncthreads();
  if (tid == 0) {
    partial[2 * blockIdx.x]     = red[0] + red[2] + red[4] + red[6];
    partial[2 * blockIdx.x + 1] = red[1] + red[3] + red[5] + red[7];
    __threadfence();                       // release partials (device scope)
    unsigned int old = atomicAdd(counter, 1u);
    amLast = (old == NBLK - 1);
  }
  __syncthreads();

  // ---- last-arriving block: deterministic fixed-order final reduce ----
  if (amLast) {
    __threadfence();                       // acquire all partials
    double s = 0.0, sa = 0.0;
    for (int i = tid; i < NBLK; i += TPB) {
      s += partial[2 * i];
      sa += partial[2 * i + 1];
    }
#pragma unroll
    for (int off = 32; off > 0; off >>= 1) {
      s += __shfl_down(s, off, 64);
      sa += __shfl_down(sa, off, 64);
    }
    if ((tid & 63) == 0) { red[wid * 2] = s; red[wid * 2 + 1] = sa; }
    __syncthreads();
    if (tid == 0) {
      double S  = red[0] + red[2] + red[4] + red[6];
      double SA = red[1] + red[3] + red[5] + red[7];
      int k = 0;
      double tt = SA;
      while (tt > 1.0 && k < 4096) { tt *= 0.5; ++k; }  // exact: /2 per ref iter
      out[0] = (float)ldexp(S, -k);
    }
  }
}

extern "C" void kernel_launch(void* const* d_in, const int* in_sizes, int n_in,
                              void* d_out, int out_size, void* d_ws, size_t ws_size,
                              hipStream_t stream) {
  const float* X = (const float*)d_in[0];
  const float* W = (const float*)d_in[1];
  const float* b = (const float*)d_in[2];
  const float* R = (const float*)d_in[3];
  char* ws = (char*)d_ws;
  double* partial = (double*)ws;
  unsigned int* counter = (unsigned int*)(ws + CNT_OFF);

  hipMemsetAsync(counter, 0, sizeof(unsigned int), stream);  // capture-legal node
  fused_kernel<<<NBLK, TPB, 0, stream>>>(X, W, b, R, partial, counter,
                                         (float*)d_out);
}

// Round 6
// 57.715 us; speedup vs baseline: 1.5604x; 1.5604x over previous
//
#include <hip/hip_runtime.h>
#include <math.h>

#define D 20
#define NROWS 1000000
#define NTILES (NROWS / 16)          // 62500 16-row tiles
#define TPB 256
#define NBLK 1024                    // proven best (R3)
#define WT (NBLK * (TPB / 64))       // 4096 waves

typedef float  f32x4  __attribute__((ext_vector_type(4)));
typedef __bf16 bf16x8 __attribute__((ext_vector_type(8)));

// ws layout (all regions written before read every launch -> poison-safe):
//   [0, NBLK*16)        : per-block partials (S, Sabs) doubles
//   [CNT_OFF, +4)       : atomic counter (memset to 0 each launch)
//   [FRAG_OFF, +4096)   : 4 MFMA constant fragments, 64 lanes x 16B each
#define CNT_OFF (NBLK * 16)
#define FRAG_OFF (CNT_OFF + 256)

__device__ inline unsigned int pk2(float a, float b) {
  unsigned short la = __builtin_bit_cast(unsigned short, (__bf16)a);
  unsigned short lb = __builtin_bit_cast(unsigned short, (__bf16)b);
  return (unsigned int)la | ((unsigned int)lb << 16);
}

// ---------------------------------------------------------------------------
// Setup (1 block, runs once): fold layers + build MFMA constant fragments.
//   A[j][m] = sum_i W[i][j]*R[i][m];  c[m] = 1 + sum_i b[i]*R[i][m]
// Fragments (16x16x32 bf16 layout: lane l holds k = (l>>4)*8+e, e=0..7):
//   B1t1/B1t2: A^T as MFMA-A-operand rows m=ii / 16+ii, k=j; k==20 slot = c[m]
//   B2t1/B2t2: W  as MFMA-B-operand cols n=ii / 16+ii, SIGMA-permuted k-rows
//     sigma(G,e)= e<4 ? 4G+e : 16+4G+(e-4); slot sigma==20 = b[n].  Permutation
//     chosen so GEMM1 accumulator regs feed GEMM2's A-fragment w/o cross-lane ops.
// ---------------------------------------------------------------------------
__global__ __launch_bounds__(512) void setup_kernel(
    const float* __restrict__ W, const float* __restrict__ b,
    const float* __restrict__ R, unsigned int* __restrict__ frags) {
  __shared__ float A_s[D * D];
  __shared__ float c_s[D];
  const int t = threadIdx.x;
  if (t < D * D) {
    int j = t / D, m = t % D;
    float s = 0.f;
#pragma unroll
    for (int i = 0; i < D; ++i) s = fmaf(W[i * D + j], R[i * D + m], s);
    A_s[j * D + m] = s;
  } else if (t < D * D + D) {
    int m = t - D * D;
    float s = 1.0f;
#pragma unroll
    for (int i = 0; i < D; ++i) s = fmaf(b[i], R[i * D + m], s);
    c_s[m] = s;
  }
  __syncthreads();
  if (t < 64) {
    const int G = t >> 4, ii = t & 15;
    uint4* out = (uint4*)frags;
    unsigned w[4];
    // ---- B1t1: rows m = ii ----
    for (int wd = 0; wd < 4; ++wd) {
      float v[2];
      for (int h = 0; h < 2; ++h) {
        int k = G * 8 + 2 * wd + h;
        v[h] = (k < D) ? A_s[k * D + ii] : (k == D ? c_s[ii] : 0.f);
      }
      w[wd] = pk2(v[0], v[1]);
    }
    out[t] = make_uint4(w[0], w[1], w[2], w[3]);
    // ---- B1t2: rows m = 16+ii (zero if >=20) ----
    for (int wd = 0; wd < 4; ++wd) {
      float v[2];
      for (int h = 0; h < 2; ++h) {
        int k = G * 8 + 2 * wd + h;
        int m = 16 + ii;
        v[h] = (m < D) ? ((k < D) ? A_s[k * D + m] : (k == D ? c_s[m] : 0.f)) : 0.f;
      }
      w[wd] = pk2(v[0], v[1]);
    }
    out[64 + t] = make_uint4(w[0], w[1], w[2], w[3]);
    // ---- B2t1: cols n = ii, sigma-permuted k-rows ----
    for (int wd = 0; wd < 4; ++wd) {
      float v[2];
      for (int h = 0; h < 2; ++h) {
        int e = 2 * wd + h;
        int sg = (e < 4) ? (4 * G + e) : (16 + 4 * G + (e - 4));
        v[h] = (sg < D) ? W[ii * D + sg] : (sg == D ? b[ii] : 0.f);
      }
      w[wd] = pk2(v[0], v[1]);
    }
    out[128 + t] = make_uint4(w[0], w[1], w[2], w[3]);
    // ---- B2t2: cols n = 16+ii (zero if >=20) ----
    for (int wd = 0; wd < 4; ++wd) {
      float v[2];
      for (int h = 0; h < 2; ++h) {
        int e = 2 * wd + h;
        int sg = (e < 4) ? (4 * G + e) : (16 + 4 * G + (e - 4));
        int n = 16 + ii;
        v[h] = (n < D) ? ((sg < D) ? W[n * D + sg] : (sg == D ? b[n] : 0.f)) : 0.f;
      }
      w[wd] = pk2(v[0], v[1]);
    }
    out[192 + t] = make_uint4(w[0], w[1], w[2], w[3]);
  }
}

// ---------------------------------------------------------------------------
// Main (R3 loop, verbatim) + fused finalize (R4-proven atomic last-block):
//   X-frag: lane l holds X[r=l&15][k=G*8+e] (k==20 -> 1.0 for the c-slot)
//   GEMM1 (transposed): a1/a2 = mfma(B1t*, Xfrag) -> lane holds
//       X2[r=l&15][4G+reg] and X2[r][16+4G+reg]  (== GEMM2 A-frag slots!)
//   relu; hijack m=20 slot (G==1, reg0) to 1.0 for the b-row.
//   GEMM2: z = mfma(X2frag, B2t*) -> Z[4G+reg][n]; sum / abs-sum.
// ---------------------------------------------------------------------------
__global__ __launch_bounds__(TPB) void main_kernel(
    const float* __restrict__ X, const unsigned int* __restrict__ frags,
    double* __restrict__ partial, unsigned int* __restrict__ counter,
    float* __restrict__ out) {
  const int tid = threadIdx.x;
  const int lane = tid & 63;
  const int G = lane >> 4, ii = lane & 15;
  const int wid = tid >> 6;
  const int gwave = blockIdx.x * (TPB / 64) + wid;

  const uint4* fr = (const uint4*)frags;
  const bf16x8 B1t1 = __builtin_bit_cast(bf16x8, fr[lane]);
  const bf16x8 B1t2 = __builtin_bit_cast(bf16x8, fr[64 + lane]);
  const bf16x8 B2t1 = __builtin_bit_cast(bf16x8, fr[128 + lane]);
  const bf16x8 B2t2 = __builtin_bit_cast(bf16x8, fr[192 + lane]);

  const int g8 = (G < 2) ? G * 8 : 16;
  double s64 = 0.0, sa64 = 0.0;

  // one-tile-ahead prefetch of this lane's 16B(+16B) slice
  float4 xa = {0.f, 0.f, 0.f, 0.f}, xb = {0.f, 0.f, 0.f, 0.f};
  if (gwave < NTILES) {
    const float* p = X + (size_t)(gwave * 16 + ii) * D + g8;
    if (G < 3) xa = *(const float4*)p;
    if (G < 2) xb = *(const float4*)(p + 4);
  }

  for (int t = gwave; t < NTILES; t += WT) {
    const float4 ca = xa, cb = xb;
    const int tn = t + WT;
    xa = (float4){0.f, 0.f, 0.f, 0.f};
    xb = (float4){0.f, 0.f, 0.f, 0.f};
    if (tn < NTILES) {
      const float* p = X + (size_t)(tn * 16 + ii) * D + g8;
      if (G < 3) xa = *(const float4*)p;
      if (G < 2) xb = *(const float4*)(p + 4);
    }
    // build X fragment (c-slot k=20 -> 1.0 on G==2/e==4)
    const float e4 = (G == 2) ? 1.0f : cb.x;
    bf16x8 xf;
    xf[0] = (__bf16)ca.x; xf[1] = (__bf16)ca.y;
    xf[2] = (__bf16)ca.z; xf[3] = (__bf16)ca.w;
    xf[4] = (__bf16)e4;   xf[5] = (__bf16)cb.y;
    xf[6] = (__bf16)cb.z; xf[7] = (__bf16)cb.w;

    const f32x4 zz = {0.f, 0.f, 0.f, 0.f};
    f32x4 a1 = __builtin_amdgcn_mfma_f32_16x16x32_bf16(B1t1, xf, zz, 0, 0, 0);
    f32x4 a2 = __builtin_amdgcn_mfma_f32_16x16x32_bf16(B1t2, xf, zz, 0, 0, 0);
#pragma unroll
    for (int q = 0; q < 4; ++q) {
      a1[q] = fmaxf(a1[q], 0.f);
      a2[q] = fmaxf(a2[q], 0.f);
    }
    const float hj = (G == 1) ? 1.0f : a2[0];  // m=20 slot carries 1.0 (b-row)
    bf16x8 x2f;
    x2f[0] = (__bf16)a1[0]; x2f[1] = (__bf16)a1[1];
    x2f[2] = (__bf16)a1[2]; x2f[3] = (__bf16)a1[3];
    x2f[4] = (__bf16)hj;    x2f[5] = (__bf16)a2[1];
    x2f[6] = (__bf16)a2[2]; x2f[7] = (__bf16)a2[3];

    f32x4 z1 = __builtin_amdgcn_mfma_f32_16x16x32_bf16(x2f, B2t1, zz, 0, 0, 0);
    f32x4 z2 = __builtin_amdgcn_mfma_f32_16x16x32_bf16(x2f, B2t2, zz, 0, 0, 0);

    const float s8 = ((z1[0] + z1[1]) + (z1[2] + z1[3])) +
                     ((z2[0] + z2[1]) + (z2[2] + z2[3]));
    const float sa8 =
        ((fabsf(z1[0]) + fabsf(z1[1])) + (fabsf(z1[2]) + fabsf(z1[3]))) +
        ((fabsf(z2[0]) + fabsf(z2[1])) + (fabsf(z2[2]) + fabsf(z2[3])));
    s64 += (double)s8;
    sa64 += (double)sa8;
  }

  // ---- block reduce: wave64 shfl (f64) -> 4-wave LDS -> one pair/block ----
#pragma unroll
  for (int off = 32; off > 0; off >>= 1) {
    s64 += __shfl_down(s64, off, 64);
    sa64 += __shfl_down(sa64, off, 64);
  }
  __shared__ double red[8];
  __shared__ int amLast;
  if ((tid & 63) == 0) { red[wid * 2] = s64; red[wid * 2 + 1] = sa64; }
  __syncthreads();
  if (tid == 0) {
    partial[2 * blockIdx.x]     = red[0] + red[2] + red[4] + red[6];
    partial[2 * blockIdx.x + 1] = red[1] + red[3] + red[5] + red[7];
    __threadfence();                       // release partials (device scope)
    unsigned int old = atomicAdd(counter, 1u);
    amLast = (old == NBLK - 1);
  }
  __syncthreads();

  // ---- last-arriving block: deterministic fixed-order final reduce ----
  if (amLast) {
    __threadfence();                       // acquire all partials
    double s = 0.0, sa = 0.0;
    for (int i = tid; i < NBLK; i += TPB) {
      s += partial[2 * i];
      sa += partial[2 * i + 1];
    }
#pragma unroll
    for (int off = 32; off > 0; off >>= 1) {
      s += __shfl_down(s, off, 64);
      sa += __shfl_down(sa, off, 64);
    }
    if ((tid & 63) == 0) { red[wid * 2] = s; red[wid * 2 + 1] = sa; }
    __syncthreads();
    if (tid == 0) {
      double S  = red[0] + red[2] + red[4] + red[6];
      double SA = red[1] + red[3] + red[5] + red[7];
      int k = 0;
      double tt = SA;
      while (tt > 1.0 && k < 4096) { tt *= 0.5; ++k; }  // exact: /2 per ref iter
      out[0] = (float)ldexp(S, -k);
    }
  }
}

extern "C" void kernel_launch(void* const* d_in, const int* in_sizes, int n_in,
                              void* d_out, int out_size, void* d_ws, size_t ws_size,
                              hipStream_t stream) {
  const float* X = (const float*)d_in[0];
  const float* W = (const float*)d_in[1];
  const float* b = (const float*)d_in[2];
  const float* R = (const float*)d_in[3];
  char* ws = (char*)d_ws;
  double* partial = (double*)ws;
  unsigned int* counter = (unsigned int*)(ws + CNT_OFF);
  unsigned int* frags = (unsigned int*)(ws + FRAG_OFF);

  hipMemsetAsync(counter, 0, sizeof(unsigned int), stream);  // capture-legal node
  setup_kernel<<<1, 512, 0, stream>>>(W, b, R, frags);
  main_kernel<<<NBLK, TPB, 0, stream>>>(X, frags, partial, counter,
                                        (float*)d_out);
}

// Round 7
// 30.978 us; speedup vs baseline: 2.9072x; 1.8631x over previous
//
#include <hip/hip_runtime.h>
#include <math.h>

#define D 20
#define NROWS 1000000
#define NTILES (NROWS / 16)            // 62500 16-row tiles
#define TPB 256
#define TILES_PER_BLK 16               // 16 tiles * 1280 B = 20 KB staged/block
#define NSB ((NTILES + TILES_PER_BLK - 1) / TILES_PER_BLK)   // 3907 blocks
#define NF4 (NROWS * D / 4)            // 5,000,000 float4s in X
#define F4_PER_SB (TILES_PER_BLK * 16 * D / 4)               // 1280 float4/superblock

typedef float  f32x4  __attribute__((ext_vector_type(4)));
typedef __bf16 bf16x8 __attribute__((ext_vector_type(8)));

// ws layout (all regions written before read every launch -> poison-safe):
//   [0, NSB*16)       : per-block partials (S, Sabs) doubles = 62512 B
//   [65536, +4096)    : 4 MFMA constant fragments, 64 lanes x 16B each
#define FRAG_OFF 65536

__device__ inline unsigned int pk2(float a, float b) {
  unsigned short la = __builtin_bit_cast(unsigned short, (__bf16)a);
  unsigned short lb = __builtin_bit_cast(unsigned short, (__bf16)b);
  return (unsigned int)la | ((unsigned int)lb << 16);
}

// ---------------------------------------------------------------------------
// Setup (1 block, once): fold layers + build MFMA constant fragments.
//   A[j][m] = sum_i W[i][j]*R[i][m];  c[m] = 1 + sum_i b[i]*R[i][m]
// Fragments (16x16x32 bf16: lane l holds k=(l>>4)*8+e):
//   B1t1/B1t2: A^T rows m=ii/16+ii, k=j; k==20 slot = c[m]
//   B2t1/B2t2: W cols n=ii/16+ii, SIGMA-permuted k-rows
//     sigma(G,e)= e<4 ? 4G+e : 16+4G+(e-4); slot sigma==20 = b[n]
//   (permutation makes GEMM1 acc regs feed GEMM2 A-frag with no cross-lane ops)
// ---------------------------------------------------------------------------
__global__ __launch_bounds__(512) void setup_kernel(
    const float* __restrict__ W, const float* __restrict__ b,
    const float* __restrict__ R, unsigned int* __restrict__ frags) {
  __shared__ float A_s[D * D];
  __shared__ float c_s[D];
  const int t = threadIdx.x;
  if (t < D * D) {
    int j = t / D, m = t % D;
    float s = 0.f;
#pragma unroll
    for (int i = 0; i < D; ++i) s = fmaf(W[i * D + j], R[i * D + m], s);
    A_s[j * D + m] = s;
  } else if (t < D * D + D) {
    int m = t - D * D;
    float s = 1.0f;
#pragma unroll
    for (int i = 0; i < D; ++i) s = fmaf(b[i], R[i * D + m], s);
    c_s[m] = s;
  }
  __syncthreads();
  if (t < 64) {
    const int G = t >> 4, ii = t & 15;
    uint4* out = (uint4*)frags;
    unsigned w[4];
    for (int wd = 0; wd < 4; ++wd) {            // B1t1: rows m = ii
      float v[2];
      for (int h = 0; h < 2; ++h) {
        int k = G * 8 + 2 * wd + h;
        v[h] = (k < D) ? A_s[k * D + ii] : (k == D ? c_s[ii] : 0.f);
      }
      w[wd] = pk2(v[0], v[1]);
    }
    out[t] = make_uint4(w[0], w[1], w[2], w[3]);
    for (int wd = 0; wd < 4; ++wd) {            // B1t2: rows m = 16+ii
      float v[2];
      for (int h = 0; h < 2; ++h) {
        int k = G * 8 + 2 * wd + h;
        int m = 16 + ii;
        v[h] = (m < D) ? ((k < D) ? A_s[k * D + m] : (k == D ? c_s[m] : 0.f)) : 0.f;
      }
      w[wd] = pk2(v[0], v[1]);
    }
    out[64 + t] = make_uint4(w[0], w[1], w[2], w[3]);
    for (int wd = 0; wd < 4; ++wd) {            // B2t1: cols n = ii
      float v[2];
      for (int h = 0; h < 2; ++h) {
        int e = 2 * wd + h;
        int sg = (e < 4) ? (4 * G + e) : (16 + 4 * G + (e - 4));
        v[h] = (sg < D) ? W[ii * D + sg] : (sg == D ? b[ii] : 0.f);
      }
      w[wd] = pk2(v[0], v[1]);
    }
    out[128 + t] = make_uint4(w[0], w[1], w[2], w[3]);
    for (int wd = 0; wd < 4; ++wd) {            // B2t2: cols n = 16+ii
      float v[2];
      for (int h = 0; h < 2; ++h) {
        int e = 2 * wd + h;
        int sg = (e < 4) ? (4 * G + e) : (16 + 4 * G + (e - 4));
        int n = 16 + ii;
        v[h] = (n < D) ? ((sg < D) ? W[n * D + sg] : (sg == D ? b[n] : 0.f)) : 0.f;
      }
      w[wd] = pk2(v[0], v[1]);
    }
    out[192 + t] = make_uint4(w[0], w[1], w[2], w[3]);
  }
}

// ---------------------------------------------------------------------------
// Main: one block = one 16-tile superblock (20 KB of X).
//   stage:   5 fully-coalesced float4 loads/thread -> LDS (contig ds_write_b128)
//   compute: wave w handles tiles 4w..4w+3; per tile 2 ds_read_b128 (strided in
//            LDS = cheap), branchless masked fragment build, 4 MFMAs, sums.
// No grid-stride loop: block turnover pipelines staging of later superblocks
// under compute of earlier ones. 20.6 KB LDS -> 7 blocks/CU.
// ---------------------------------------------------------------------------
__global__ __launch_bounds__(TPB) void main_kernel(
    const float* __restrict__ X, const unsigned int* __restrict__ frags,
    double* __restrict__ partial) {
  __shared__ float4 xs4[F4_PER_SB + 8];          // 20 KB + 128 B pad (G>=2 overread)
  float* xs = (float*)xs4;
  const int t = threadIdx.x;
  const int s = blockIdx.x;

  // ---- stage: fully coalesced (lane-contiguous 16 B), clamped at X end ----
  const float4* X4 = (const float4*)X;
#pragma unroll
  for (int j = 0; j < 5; ++j) {
    int gi = s * F4_PER_SB + j * TPB + t;
    gi = (gi < NF4) ? gi : (NF4 - 1);            // tail: garbage, guarded below
    xs4[j * TPB + t] = X4[gi];
  }

  // frag loads overlap the staging latency
  const int lane = t & 63;
  const int G = lane >> 4, ii = lane & 15;
  const int wid = t >> 6;
  const uint4* fr = (const uint4*)frags;
  const bf16x8 B1t1 = __builtin_bit_cast(bf16x8, fr[lane]);
  const bf16x8 B1t2 = __builtin_bit_cast(bf16x8, fr[64 + lane]);
  const bf16x8 B2t1 = __builtin_bit_cast(bf16x8, fr[128 + lane]);
  const bf16x8 B2t2 = __builtin_bit_cast(bf16x8, fr[192 + lane]);
  __syncthreads();

  // ---- compute: 4 tiles per wave, fragments gathered from LDS ----
  const bool mA = (G < 3);                       // xf[0..3] valid
  const bool mB = (G < 2);                       // xf[5..7] valid, xf[4]=cb.x
  const int gf = (G < 2) ? G * 8 : 16;           // float offset in row (clamped)
  const float* rowp = xs + ii * D + gf;
  const int tbase = s * TILES_PER_BLK + wid * 4;
  double s64 = 0.0, sa64 = 0.0;

#pragma unroll
  for (int k = 0; k < 4; ++k) {
    if (tbase + k < NTILES) {                    // wave-uniform guard (tail)
      const float* p = rowp + (wid * 4 + k) * (16 * D);
      const float4 ca = *(const float4*)p;       // ds_read_b128
      const float4 cb = *(const float4*)(p + 4); // ds_read_b128 (G>=2: garbage, masked)

      bf16x8 xf;                                 // k = G*8+e; k==20 -> 1.0; k>20 -> 0
      xf[0] = (__bf16)(mA ? ca.x : 0.f);
      xf[1] = (__bf16)(mA ? ca.y : 0.f);
      xf[2] = (__bf16)(mA ? ca.z : 0.f);
      xf[3] = (__bf16)(mA ? ca.w : 0.f);
      xf[4] = (__bf16)(mB ? cb.x : (G == 2 ? 1.0f : 0.f));
      xf[5] = (__bf16)(mB ? cb.y : 0.f);
      xf[6] = (__bf16)(mB ? cb.z : 0.f);
      xf[7] = (__bf16)(mB ? cb.w : 0.f);

      const f32x4 zz = {0.f, 0.f, 0.f, 0.f};
      f32x4 a1 = __builtin_amdgcn_mfma_f32_16x16x32_bf16(B1t1, xf, zz, 0, 0, 0);
      f32x4 a2 = __builtin_amdgcn_mfma_f32_16x16x32_bf16(B1t2, xf, zz, 0, 0, 0);
#pragma unroll
      for (int q = 0; q < 4; ++q) {
        a1[q] = fmaxf(a1[q], 0.f);
        a2[q] = fmaxf(a2[q], 0.f);
      }
      const float hj = (G == 1) ? 1.0f : a2[0];  // m=20 slot carries 1.0 (b-row)
      bf16x8 x2f;
      x2f[0] = (__bf16)a1[0]; x2f[1] = (__bf16)a1[1];
      x2f[2] = (__bf16)a1[2]; x2f[3] = (__bf16)a1[3];
      x2f[4] = (__bf16)hj;    x2f[5] = (__bf16)a2[1];
      x2f[6] = (__bf16)a2[2]; x2f[7] = (__bf16)a2[3];

      f32x4 z1 = __builtin_amdgcn_mfma_f32_16x16x32_bf16(x2f, B2t1, zz, 0, 0, 0);
      f32x4 z2 = __builtin_amdgcn_mfma_f32_16x16x32_bf16(x2f, B2t2, zz, 0, 0, 0);

      const float s8 = ((z1[0] + z1[1]) + (z1[2] + z1[3])) +
                       ((z2[0] + z2[1]) + (z2[2] + z2[3]));
      const float sa8 =
          ((fabsf(z1[0]) + fabsf(z1[1])) + (fabsf(z1[2]) + fabsf(z1[3]))) +
          ((fabsf(z2[0]) + fabsf(z2[1])) + (fabsf(z2[2]) + fabsf(z2[3])));
      s64 += (double)s8;
      sa64 += (double)sa8;
    }
  }

  // ---- block reduce: wave64 shfl (f64) -> 4-wave LDS -> one pair/block ----
#pragma unroll
  for (int off = 32; off > 0; off >>= 1) {
    s64 += __shfl_down(s64, off, 64);
    sa64 += __shfl_down(sa64, off, 64);
  }
  __shared__ double red[8];
  if ((t & 63) == 0) { red[wid * 2] = s64; red[wid * 2 + 1] = sa64; }
  __syncthreads();
  if (t == 0) {
    partial[2 * s]     = red[0] + red[2] + red[4] + red[6];
    partial[2 * s + 1] = red[1] + red[3] + red[5] + red[7];
  }
}

// ---------------------------------------------------------------------------
// Finalize: reduce NSB partial pairs; while-loop is exact scalar math:
// k = #halvings until abs-sum <= 1; out = ldexp(S, -k).
// ---------------------------------------------------------------------------
__global__ __launch_bounds__(256) void final_kernel(
    const double* __restrict__ partial, float* __restrict__ out) {
  double s = 0.0, sa = 0.0;
  for (int i = threadIdx.x; i < NSB; i += 256) {
    s += partial[2 * i];
    sa += partial[2 * i + 1];
  }
#pragma unroll
  for (int off = 32; off > 0; off >>= 1) {
    s += __shfl_down(s, off, 64);
    sa += __shfl_down(sa, off, 64);
  }
  __shared__ double red[8];
  int wid = threadIdx.x >> 6;
  if ((threadIdx.x & 63) == 0) { red[wid * 2] = s; red[wid * 2 + 1] = sa; }
  __syncthreads();
  if (threadIdx.x == 0) {
    double S  = red[0] + red[2] + red[4] + red[6];
    double SA = red[1] + red[3] + red[5] + red[7];
    int k = 0;
    double t = SA;
    while (t > 1.0 && k < 4096) { t *= 0.5; ++k; }  // exact: /2 per ref iter
    out[0] = (float)ldexp(S, -k);
  }
}

extern "C" void kernel_launch(void* const* d_in, const int* in_sizes, int n_in,
                              void* d_out, int out_size, void* d_ws, size_t ws_size,
                              hipStream_t stream) {
  const float* X = (const float*)d_in[0];
  const float* W = (const float*)d_in[1];
  const float* b = (const float*)d_in[2];
  const float* R = (const float*)d_in[3];
  char* ws = (char*)d_ws;
  double* partial = (double*)ws;
  unsigned int* frags = (unsigned int*)(ws + FRAG_OFF);

  setup_kernel<<<1, 512, 0, stream>>>(W, b, R, frags);
  main_kernel<<<NSB, TPB, 0, stream>>>(X, frags, partial);
  final_kernel<<<1, 256, 0, stream>>>(partial, (float*)d_out);
}